// Round 2
// baseline (541.379 us; speedup 1.0000x reference)
//
#include <hip/hip_runtime.h>

#define NB 4
#define NN 20000
#define NE 16
#define NC 128
#define M_TOTAL (NB * NN)
#define BM 64
#define LDS_S (NC + 4) /* 132 */
#define NWG (M_TOTAL / BM) /* 1250 */

// ---------------- inv-sqrt-degree ----------------
__global__ __launch_bounds__(256) void isd_kernel(const int* __restrict__ ei,
                                                  float* __restrict__ isd) {
    int g = blockIdx.x * 256 + threadIdx.x;
    if (g >= M_TOTAL) return;
    const int4* e4 = (const int4*)(ei + (size_t)g * NE);
    int cnt = 1;  // self
#pragma unroll
    for (int q = 0; q < 4; ++q) {
        int4 v = e4[q];
        cnt += (v.x >= 0) + (v.y >= 0) + (v.z >= 0) + (v.w >= 0);
    }
    isd[g] = 1.0f / sqrtf((float)cnt);
}

// ---------------- W[o][c] -> Wt[c][o] (64KB, L2-resident) ----------------
__global__ __launch_bounds__(256) void wt_kernel(const float* __restrict__ W,
                                                 float* __restrict__ Wt) {
    const int i = blockIdx.x * 256 + threadIdx.x;  // 16384 elems
    // coalesced write, strided (L1/L2-cached) read
    Wt[i] = W[(i & (NC - 1)) * NC + (i >> 7)];
}

// ---------------- fused GCN layer ----------------
// out_g = elu( isd_g * ( (sum_{j in N(g)} isd_j x_j + isd_g x_g) . W^T ) )
__global__ __launch_bounds__(256, 4) void gcn_layer_kernel(
    const float* __restrict__ X, const int* __restrict__ ei,
    const float* __restrict__ isd, const float* __restrict__ wt,
    float* __restrict__ out) {
    __shared__ float S[BM][LDS_S];
    const int t = threadIdx.x;

    // bijective XCD-chunked swizzle over 1250 workgroups (q=156, r=2)
    const int bid = blockIdx.x;
    const int q = NWG >> 3, r = NWG & 7;
    const int xcd = bid & 7, idx = bid >> 3;
    const int wg = (xcd < r ? xcd * (q + 1) : r * (q + 1) + (xcd - r) * q) + idx;
    const int bm = wg * BM;

    // ---- phase 1: gather-aggregate 64 rows into LDS ----
    {
        const int w = t >> 6, l = t & 63;
        const float2* x2 = (const float2*)X;
        for (int s = 0; s < 16; ++s) {
            int g = bm + w * 16 + s;
            g = __builtin_amdgcn_readfirstlane(g);
            const int base = (g / NN) * NN;
            const int4* e4 = (const int4*)(ei + (size_t)g * NE);
            const int4 ea = e4[0], eb = e4[1], ec = e4[2], ed = e4[3];
            const int e[NE] = {ea.x, ea.y, ea.z, ea.w, eb.x, eb.y, eb.z, eb.w,
                               ec.x, ec.y, ec.z, ec.w, ed.x, ed.y, ed.z, ed.w};
            const float sdg = isd[g];
            const float2 v = x2[(size_t)g * 64 + l];
            float2 acc;
            acc.x = sdg * v.x;
            acc.y = sdg * v.y;
#pragma unroll
            for (int k2 = 0; k2 < NE; ++k2) {
                const int nb = e[k2];
                const int row = base + (nb & ~(nb >> 31));  // base + max(nb,0)
                float sd = isd[row];
                if (nb < 0) sd = 0.0f;  // wave-uniform predicate
                const float2 u = x2[(size_t)row * 64 + l];
                acc.x = fmaf(sd, u.x, acc.x);
                acc.y = fmaf(sd, u.y, acc.y);
            }
            *(float2*)(&S[w * 16 + s][l * 2]) = acc;
        }
    }
    __syncthreads();

    // ---- phase 2: out-tile = elu( (S . Wt) * isd_g ), Wt read from global ----
    const int tx = t & 15;        // o-group: o = tx*8 .. tx*8+7
    const int m0 = (t >> 4) * 4;  // 4 consecutive rows per thread
    float acc[4][8];
#pragma unroll
    for (int i = 0; i < 4; ++i)
#pragma unroll
        for (int j = 0; j < 8; ++j) acc[i][j] = 0.0f;

    const float4* wt4 = (const float4*)wt;
#pragma unroll 8
    for (int kl = 0; kl < NC; ++kl) {
        const float a0 = S[m0 + 0][kl];
        const float a1 = S[m0 + 1][kl];
        const float a2 = S[m0 + 2][kl];
        const float a3 = S[m0 + 3][kl];
        const float4 wlo = wt4[kl * 32 + tx * 2];
        const float4 whi = wt4[kl * 32 + tx * 2 + 1];
        const float wv[8] = {wlo.x, wlo.y, wlo.z, wlo.w,
                             whi.x, whi.y, whi.z, whi.w};
#pragma unroll
        for (int j = 0; j < 8; ++j) {
            acc[0][j] = fmaf(a0, wv[j], acc[0][j]);
            acc[1][j] = fmaf(a1, wv[j], acc[1][j]);
            acc[2][j] = fmaf(a2, wv[j], acc[2][j]);
            acc[3][j] = fmaf(a3, wv[j], acc[3][j]);
        }
    }

#pragma unroll
    for (int i = 0; i < 4; ++i) {
        const int m = bm + m0 + i;
        const float sd = isd[m];
        float v[8];
#pragma unroll
        for (int j = 0; j < 8; ++j) {
            float y = acc[i][j] * sd;
            v[j] = y > 0.0f ? y : (__expf(y) - 1.0f);
        }
        float4 o0 = {v[0], v[1], v[2], v[3]};
        float4 o1 = {v[4], v[5], v[6], v[7]};
        *(float4*)(out + (size_t)m * NC + tx * 8) = o0;
        *(float4*)(out + (size_t)m * NC + tx * 8 + 4) = o1;
    }
}

extern "C" void kernel_launch(void* const* d_in, const int* in_sizes, int n_in,
                              void* d_out, int out_size, void* d_ws, size_t ws_size,
                              hipStream_t stream) {
    const float* x = (const float*)d_in[0];
    const int* ei = (const int*)d_in[1];
    const float* W0 = (const float*)d_in[2];
    const float* W1 = (const float*)d_in[3];
    const float* W2 = (const float*)d_in[4];
    float* out = (float*)d_out;

    float* isd = (float*)d_ws;                               // 320 KB
    float* wt0 = (float*)((char*)d_ws + (320 << 10));        // 64 KB
    float* wt1 = (float*)((char*)d_ws + (384 << 10));        // 64 KB
    float* wt2 = (float*)((char*)d_ws + (448 << 10));        // 64 KB
    float* h = (float*)((char*)d_ws + (512 << 10));          // 40.96 MB

    isd_kernel<<<(M_TOTAL + 255) / 256, 256, 0, stream>>>(ei, isd);
    wt_kernel<<<NC * NC / 256, 256, 0, stream>>>(W0, wt0);
    wt_kernel<<<NC * NC / 256, 256, 0, stream>>>(W1, wt1);
    wt_kernel<<<NC * NC / 256, 256, 0, stream>>>(W2, wt2);

    // L0: x -> d_out ; L1: d_out -> h ; L2: h -> d_out
    gcn_layer_kernel<<<NWG, 256, 0, stream>>>(x, ei, isd, wt0, out);
    gcn_layer_kernel<<<NWG, 256, 0, stream>>>(out, ei, isd, wt1, h);
    gcn_layer_kernel<<<NWG, 256, 0, stream>>>(h, ei, isd, wt2, out);
}

// Round 3
// 433.829 us; speedup vs baseline: 1.2479x; 1.2479x over previous
//
#include <hip/hip_runtime.h>

#define NB 4
#define NN 20000
#define NE 16
#define NC 128
#define M_TOTAL (NB * NN)

#define BM 64
#define BK 32
#define LDA (BM + 4)  /* 68: row stride 272B = 17x16B, keeps b128 alignment */
#define LDW (NC + 4)  /* 132: row stride 528B = 33x16B */

// ---------------- inv-sqrt-degree ----------------
__global__ __launch_bounds__(256) void isd_kernel(const int* __restrict__ ei,
                                                  float* __restrict__ isd) {
    int g = blockIdx.x * 256 + threadIdx.x;
    if (g >= M_TOTAL) return;
    const int4* e4 = (const int4*)(ei + (size_t)g * NE);
    int cnt = 1;  // self
#pragma unroll
    for (int q = 0; q < 4; ++q) {
        int4 v = e4[q];
        cnt += (v.x >= 0) + (v.y >= 0) + (v.z >= 0) + (v.w >= 0);
    }
    isd[g] = 1.0f / sqrtf((float)cnt);
}

// ---------------- H = (X @ W^T) * isd ----------------
// H[m][o] = (sum_c X[m][c] * W[o][c]) * isd[m]
// 256 threads: tx = t&15 -> o = tx*8..+7 ; ty = t>>4 -> m = ty*4..+3
__global__ __launch_bounds__(256, 4) void matmul_kernel(const float* __restrict__ X,
                                                        const float* __restrict__ W,
                                                        const float* __restrict__ isd,
                                                        float* __restrict__ H) {
    __shared__ float At[BK][LDA];  // A transposed: At[k_local][m]
    __shared__ float Ws[BK][LDW];  // W transposed: Ws[k_local][o]
    const int t = threadIdx.x;
    const int tx = t & 15;
    const int ty = t >> 4;
    const int bm = blockIdx.x * BM;

    float acc[4][8];
#pragma unroll
    for (int i = 0; i < 4; ++i)
#pragma unroll
        for (int j = 0; j < 8; ++j) acc[i][j] = 0.0f;

    for (int kk = 0; kk < NC; kk += BK) {
        __syncthreads();  // protect tiles from previous chunk's readers
        // stage A chunk: 64 rows x 32 cols, transposed into At
        {
            const int m = t >> 2;            // 0..63
            const int c4 = (t & 3) << 3;     // 0,8,16,24
#pragma unroll
            for (int h = 0; h < 2; ++h) {
                const float4 v = *(const float4*)(X + (size_t)(bm + m) * NC + kk + c4 + h * 4);
                At[c4 + h * 4 + 0][m] = v.x;
                At[c4 + h * 4 + 1][m] = v.y;
                At[c4 + h * 4 + 2][m] = v.z;
                At[c4 + h * 4 + 3][m] = v.w;
            }
        }
        // stage W chunk: 128 o-rows x 32 cols, transposed into Ws
        {
            const int o = t >> 1;            // 0..127
            const int c4 = (t & 1) << 4;     // 0,16
#pragma unroll
            for (int h = 0; h < 4; ++h) {
                const float4 v = *(const float4*)(W + (size_t)o * NC + kk + c4 + h * 4);
                Ws[c4 + h * 4 + 0][o] = v.x;
                Ws[c4 + h * 4 + 1][o] = v.y;
                Ws[c4 + h * 4 + 2][o] = v.z;
                Ws[c4 + h * 4 + 3][o] = v.w;
            }
        }
        __syncthreads();
#pragma unroll
        for (int kl = 0; kl < BK; ++kl) {
            const float4 a = *(const float4*)(&At[kl][ty << 2]);
            const float4 w0 = *(const float4*)(&Ws[kl][tx << 3]);
            const float4 w1 = *(const float4*)(&Ws[kl][(tx << 3) + 4]);
            const float av[4] = {a.x, a.y, a.z, a.w};
            const float wv[8] = {w0.x, w0.y, w0.z, w0.w, w1.x, w1.y, w1.z, w1.w};
#pragma unroll
            for (int i = 0; i < 4; ++i)
#pragma unroll
                for (int j = 0; j < 8; ++j)
                    acc[i][j] = fmaf(av[i], wv[j], acc[i][j]);
        }
    }

#pragma unroll
    for (int i = 0; i < 4; ++i) {
        const int m = bm + (ty << 2) + i;
        const float sd = isd[m];
        float4 o0, o1;
        o0.x = acc[i][0] * sd; o0.y = acc[i][1] * sd;
        o0.z = acc[i][2] * sd; o0.w = acc[i][3] * sd;
        o1.x = acc[i][4] * sd; o1.y = acc[i][5] * sd;
        o1.z = acc[i][6] * sd; o1.w = acc[i][7] * sd;
        *(float4*)(H + (size_t)m * NC + (tx << 3)) = o0;
        *(float4*)(H + (size_t)m * NC + (tx << 3) + 4) = o1;
    }
}

// ---------------- out = elu((gather_sum(H) + H_self) * isd) ----------------
// one wave per node; lane holds float2 (128 ch / 64 lanes)
__global__ __launch_bounds__(256) void gather_kernel(const float* __restrict__ H,
                                                     const int* __restrict__ ei,
                                                     const float* __restrict__ isd,
                                                     float* __restrict__ out) {
    const int wid = threadIdx.x >> 6;
    const int lane = threadIdx.x & 63;
    int g = blockIdx.x * 4 + wid;
    g = __builtin_amdgcn_readfirstlane(g);
    const int base = (g / NN) * NN;

    const int4* e4 = (const int4*)(ei + (size_t)g * NE);
    const int4 ea = e4[0], eb = e4[1], ec = e4[2], ed = e4[3];
    const int e[NE] = {ea.x, ea.y, ea.z, ea.w, eb.x, eb.y, eb.z, eb.w,
                       ec.x, ec.y, ec.z, ec.w, ed.x, ed.y, ed.z, ed.w};

    const float2* h2 = (const float2*)H;
    float2 acc = h2[(size_t)g * 64 + lane];  // self
#pragma unroll
    for (int q = 0; q < NE; ++q) {
        const int nbr = e[q];
        const int row = base + (nbr & ~(nbr >> 31));  // max(nbr,0)
        const float2 v = h2[(size_t)row * 64 + lane];
        if (nbr >= 0) { acc.x += v.x; acc.y += v.y; }  // uniform branch
    }
    const float sd = isd[g];
    acc.x *= sd; acc.y *= sd;
    acc.x = acc.x > 0.0f ? acc.x : (__expf(acc.x) - 1.0f);
    acc.y = acc.y > 0.0f ? acc.y : (__expf(acc.y) - 1.0f);
    *(float2*)(out + (size_t)g * NC + (lane << 1)) = acc;
}

extern "C" void kernel_launch(void* const* d_in, const int* in_sizes, int n_in,
                              void* d_out, int out_size, void* d_ws, size_t ws_size,
                              hipStream_t stream) {
    const float* x = (const float*)d_in[0];
    const int* ei = (const int*)d_in[1];
    const float* W0 = (const float*)d_in[2];
    const float* W1 = (const float*)d_in[3];
    const float* W2 = (const float*)d_in[4];
    float* out = (float*)d_out;

    float* isd = (float*)d_ws;
    float* h = (float*)((char*)d_ws + (1 << 19));  // +512KB; ws needs ~41.5MB

    isd_kernel<<<(M_TOTAL + 255) / 256, 256, 0, stream>>>(ei, isd);

    // layer 0: x -> h -> d_out
    matmul_kernel<<<M_TOTAL / BM, 256, 0, stream>>>(x, W0, isd, h);
    gather_kernel<<<M_TOTAL / 4, 256, 0, stream>>>(h, ei, isd, out);
    // layer 1: d_out -> h -> d_out
    matmul_kernel<<<M_TOTAL / BM, 256, 0, stream>>>(out, W1, isd, h);
    gather_kernel<<<M_TOTAL / 4, 256, 0, stream>>>(h, ei, isd, out);
    // layer 2
    matmul_kernel<<<M_TOTAL / BM, 256, 0, stream>>>(out, W2, isd, h);
    gather_kernel<<<M_TOTAL / 4, 256, 0, stream>>>(h, ei, isd, out);
}

// Round 6
// 378.178 us; speedup vs baseline: 1.4315x; 1.1472x over previous
//
#include <hip/hip_runtime.h>
#include <hip/hip_bf16.h>

#define NB 4
#define NN 20000
#define NE 16
#define NC 128
#define M_TOTAL (NB * NN)
#define BM 64

typedef __attribute__((ext_vector_type(8))) short bf16x8;
typedef __attribute__((ext_vector_type(4))) short short4v;
typedef __attribute__((ext_vector_type(4))) float f32x4;

static __device__ __forceinline__ short f2bf(float x) {
    __hip_bfloat16 h = __float2bfloat16(x);
    return *reinterpret_cast<short*>(&h);
}
static __device__ __forceinline__ float bf2f(short s) {
    __hip_bfloat16 h = *reinterpret_cast<__hip_bfloat16*>(&s);
    return __bfloat162float(h);
}

// ---------------- inv-sqrt-degree ----------------
__global__ __launch_bounds__(256) void isd_kernel(const int* __restrict__ ei,
                                                  float* __restrict__ isd) {
    int g = blockIdx.x * 256 + threadIdx.x;
    if (g >= M_TOTAL) return;
    const int4* e4 = (const int4*)(ei + (size_t)g * NE);
    int cnt = 1;  // self
#pragma unroll
    for (int q = 0; q < 4; ++q) {
        int4 v = e4[q];
        cnt += (v.x >= 0) + (v.y >= 0) + (v.z >= 0) + (v.w >= 0);
    }
    isd[g] = 1.0f / sqrtf((float)cnt);
}

// ---------------- W[o][c] -> packed split-bf16 B-fragments ----------------
// For K-step s (0..3), o-frag f (0..7), split h (0=hi,1=lo), lane l, elem e:
//   value = split_h( W[f*16 + (l&15)][s*32 + (l>>4)*8 + e] )
// flat short index: (((s*8+f)*2+h)*64 + l)*8 + e
__global__ __launch_bounds__(256) void wpack_kernel(const float* __restrict__ W,
                                                    short* __restrict__ wp) {
    const int id = blockIdx.x * 256 + threadIdx.x;  // 0..2047
    const int s = id >> 9;
    const int f = (id >> 6) & 7;
    const int l = id & 63;
    const int o = f * 16 + (l & 15);
    const int kb = s * 32 + (l >> 4) * 8;
    const float4 v0 = *(const float4*)(W + (size_t)o * NC + kb);
    const float4 v1 = *(const float4*)(W + (size_t)o * NC + kb + 4);
    const float xs[8] = {v0.x, v0.y, v0.z, v0.w, v1.x, v1.y, v1.z, v1.w};
    bf16x8 hv, lv;
#pragma unroll
    for (int e = 0; e < 8; ++e) {
        const short h = f2bf(xs[e]);
        hv[e] = h;
        lv[e] = f2bf(xs[e] - bf2f(h));
    }
    short* dst = wp + (size_t)((s * 8 + f) * 2) * 512 + l * 8;
    *(bf16x8*)dst = hv;
    *(bf16x8*)(dst + 512) = lv;
}

// ---------------- H = (X @ W^T) * isd  via 3x split-bf16 MFMA ----------------
// block: 256 thr = 4 waves; output tile 64(m) x 128(o)
// wave w: m-half = w>>1 (32 rows), o-half = w&1 (64 cols)
__global__ __launch_bounds__(256) void matmul_kernel(const float* __restrict__ X,
                                                     const short* __restrict__ wp,
                                                     const float* __restrict__ isd,
                                                     float* __restrict__ H) {
    __shared__ short Ah[64 * 128];
    __shared__ short Al[64 * 128];
    const int t = threadIdx.x;
    const int bm = blockIdx.x * BM;

    // ---- stage X tile (64x128 fp32), split to bf16 hi/lo, XOR-swizzled ----
    // flat 16B-chunks: chunk fi = j*256+t  ->  row = fi>>5, k0 = (t&31)*4
#pragma unroll
    for (int j = 0; j < 8; ++j) {
        const int fi = j * 256 + t;
        const int row = fi >> 5;
        const int k0 = (t & 31) * 4;
        const float4 v = *(const float4*)(X + (size_t)bm * NC + (size_t)fi * 4);
        const float xs[4] = {v.x, v.y, v.z, v.w};
        short4v hi, lo;
#pragma unroll
        for (int e = 0; e < 4; ++e) {
            const short h = f2bf(xs[e]);
            hi[e] = h;
            lo[e] = f2bf(xs[e] - bf2f(h));
        }
        const int kblk = k0 >> 3;
        const int dst = row * 128 + ((kblk ^ (row & 7)) << 3) + (k0 & 7);
        *(short4v*)(Ah + dst) = hi;
        *(short4v*)(Al + dst) = lo;
    }
    __syncthreads();

    const int w = t >> 6, l = t & 63;
    const int m0 = (w >> 1) * 32;
    const int oh = w & 1;
    const int lr = l & 15, lg = l >> 4;

    f32x4 acc[2][4];
#pragma unroll
    for (int mf = 0; mf < 2; ++mf)
#pragma unroll
        for (int fi = 0; fi < 4; ++fi) acc[mf][fi] = (f32x4){0.f, 0.f, 0.f, 0.f};

#pragma unroll
    for (int s = 0; s < 4; ++s) {
        bf16x8 a_h[2], a_l[2], b_h[4], b_l[4];
#pragma unroll
        for (int fi = 0; fi < 4; ++fi) {
            const int fg = oh * 4 + fi;
            const short* ph = wp + (size_t)((s * 8 + fg) * 2) * 512 + l * 8;
            b_h[fi] = *(const bf16x8*)ph;
            b_l[fi] = *(const bf16x8*)(ph + 512);
        }
#pragma unroll
        for (int mf = 0; mf < 2; ++mf) {
            const int row = m0 + mf * 16 + lr;
            const int kblk = (s * 4 + lg) ^ (l & 7);
            a_h[mf] = *(const bf16x8*)(Ah + row * 128 + kblk * 8);
            a_l[mf] = *(const bf16x8*)(Al + row * 128 + kblk * 8);
        }
#pragma unroll
        for (int mf = 0; mf < 2; ++mf)
#pragma unroll
            for (int fi = 0; fi < 4; ++fi) {
                acc[mf][fi] = __builtin_amdgcn_mfma_f32_16x16x32_bf16(
                    a_l[mf], b_h[fi], acc[mf][fi], 0, 0, 0);
                acc[mf][fi] = __builtin_amdgcn_mfma_f32_16x16x32_bf16(
                    a_h[mf], b_l[fi], acc[mf][fi], 0, 0, 0);
                acc[mf][fi] = __builtin_amdgcn_mfma_f32_16x16x32_bf16(
                    a_h[mf], b_h[fi], acc[mf][fi], 0, 0, 0);
            }
    }

    // ---- epilogue: *isd, store (C layout: col=lane&15, row=(lane>>4)*4+r) ----
#pragma unroll
    for (int mf = 0; mf < 2; ++mf)
#pragma unroll
        for (int r = 0; r < 4; ++r) {
            const int m = bm + m0 + mf * 16 + lg * 4 + r;
            const float sd = isd[m];
#pragma unroll
            for (int fi = 0; fi < 4; ++fi)
                H[(size_t)m * NC + oh * 64 + fi * 16 + lr] = acc[mf][fi][r] * sd;
        }
}

// ---------------- out = elu((gather_sum(H) + H_self) * isd) ----------------
__global__ __launch_bounds__(256) void gather_kernel(const float* __restrict__ H,
                                                     const int* __restrict__ ei,
                                                     const float* __restrict__ isd,
                                                     float* __restrict__ out) {
    const int wid = threadIdx.x >> 6;
    const int lane = threadIdx.x & 63;
    int g = blockIdx.x * 4 + wid;
    g = __builtin_amdgcn_readfirstlane(g);
    const int base = (g / NN) * NN;

    const int4* e4 = (const int4*)(ei + (size_t)g * NE);
    const int4 ea = e4[0], eb = e4[1], ec = e4[2], ed = e4[3];
    const int e[NE] = {ea.x, ea.y, ea.z, ea.w, eb.x, eb.y, eb.z, eb.w,
                       ec.x, ec.y, ec.z, ec.w, ed.x, ed.y, ed.z, ed.w};

    const float2* h2 = (const float2*)H;
    float2 acc = h2[(size_t)g * 64 + lane];  // self
#pragma unroll
    for (int q = 0; q < NE; ++q) {
        const int nbr = e[q];
        const int row = base + (nbr & ~(nbr >> 31));  // max(nbr,0)
        const float2 v = h2[(size_t)row * 64 + lane];
        if (nbr >= 0) { acc.x += v.x; acc.y += v.y; }  // uniform branch
    }
    const float sd = isd[g];
    acc.x *= sd; acc.y *= sd;
    acc.x = acc.x > 0.0f ? acc.x : (__expf(acc.x) - 1.0f);
    acc.y = acc.y > 0.0f ? acc.y : (__expf(acc.y) - 1.0f);
    *(float2*)(out + (size_t)g * NC + (lane << 1)) = acc;
}

extern "C" void kernel_launch(void* const* d_in, const int* in_sizes, int n_in,
                              void* d_out, int out_size, void* d_ws, size_t ws_size,
                              hipStream_t stream) {
    const float* x = (const float*)d_in[0];
    const int* ei = (const int*)d_in[1];
    const float* W0 = (const float*)d_in[2];
    const float* W1 = (const float*)d_in[3];
    const float* W2 = (const float*)d_in[4];
    float* out = (float*)d_out;

    float* isd = (float*)d_ws;                          // 320 KB
    short* wp0 = (short*)((char*)d_ws + (320 << 10));   // 64 KB
    short* wp1 = (short*)((char*)d_ws + (384 << 10));   // 64 KB
    short* wp2 = (short*)((char*)d_ws + (448 << 10));   // 64 KB
    float* h = (float*)((char*)d_ws + (512 << 10));     // 40.96 MB

    isd_kernel<<<(M_TOTAL + 255) / 256, 256, 0, stream>>>(ei, isd);
    wpack_kernel<<<8, 256, 0, stream>>>(W0, wp0);
    wpack_kernel<<<8, 256, 0, stream>>>(W1, wp1);
    wpack_kernel<<<8, 256, 0, stream>>>(W2, wp2);

    // layer 0: x -> h -> d_out
    matmul_kernel<<<M_TOTAL / BM, 256, 0, stream>>>(x, wp0, isd, h);
    gather_kernel<<<M_TOTAL / 4, 256, 0, stream>>>(h, ei, isd, out);
    // layer 1: d_out -> h -> d_out
    matmul_kernel<<<M_TOTAL / BM, 256, 0, stream>>>(out, wp1, isd, h);
    gather_kernel<<<M_TOTAL / 4, 256, 0, stream>>>(h, ei, isd, out);
    // layer 2
    matmul_kernel<<<M_TOTAL / BM, 256, 0, stream>>>(out, wp2, isd, h);
    gather_kernel<<<M_TOTAL / 4, 256, 0, stream>>>(h, ei, isd, out);
}

// Round 12
// 376.771 us; speedup vs baseline: 1.4369x; 1.0037x over previous
//
#include <hip/hip_runtime.h>
#include <hip/hip_bf16.h>

#define NB 4
#define NN 20000
#define NE 16
#define NC 128
#define M_TOTAL (NB * NN)
#define BM 64

typedef __attribute__((ext_vector_type(8))) short bf16x8;
typedef __attribute__((ext_vector_type(4))) short short4v;
typedef __attribute__((ext_vector_type(4))) float f32x4;

static __device__ __forceinline__ short f2bf(float x) {
    __hip_bfloat16 h = __float2bfloat16(x);
    return *reinterpret_cast<short*>(&h);
}
static __device__ __forceinline__ float bf2f(short s) {
    __hip_bfloat16 h = *reinterpret_cast<__hip_bfloat16*>(&s);
    return __bfloat162float(h);
}

// ---------------- inv-sqrt-degree ----------------
__global__ __launch_bounds__(256) void isd_kernel(const int* __restrict__ ei,
                                                  float* __restrict__ isd) {
    int g = blockIdx.x * 256 + threadIdx.x;
    if (g >= M_TOTAL) return;
    const int4* e4 = (const int4*)(ei + (size_t)g * NE);
    int cnt = 1;  // self
#pragma unroll
    for (int q = 0; q < 4; ++q) {
        int4 v = e4[q];
        cnt += (v.x >= 0) + (v.y >= 0) + (v.z >= 0) + (v.w >= 0);
    }
    isd[g] = 1.0f / sqrtf((float)cnt);
}

// ---------------- W[o][c] -> packed split-bf16 B-fragments ----------------
// K-step s (0..3), o-frag f (0..7), split h (0=hi,1=lo), lane l, elem e:
//   value = split_h( W[f*16 + (l&15)][s*32 + (l>>4)*8 + e] )
__global__ __launch_bounds__(256) void wpack_kernel(const float* __restrict__ W,
                                                    short* __restrict__ wp) {
    const int id = blockIdx.x * 256 + threadIdx.x;  // 0..2047
    const int s = id >> 9;
    const int f = (id >> 6) & 7;
    const int l = id & 63;
    const int o = f * 16 + (l & 15);
    const int kb = s * 32 + (l >> 4) * 8;
    const float4 v0 = *(const float4*)(W + (size_t)o * NC + kb);
    const float4 v1 = *(const float4*)(W + (size_t)o * NC + kb + 4);
    const float xs[8] = {v0.x, v0.y, v0.z, v0.w, v1.x, v1.y, v1.z, v1.w};
    bf16x8 hv, lv;
#pragma unroll
    for (int e = 0; e < 8; ++e) {
        const short h = f2bf(xs[e]);
        hv[e] = h;
        lv[e] = f2bf(xs[e] - bf2f(h));
    }
    short* dst = wp + (size_t)((s * 8 + f) * 2) * 512 + l * 8;
    *(bf16x8*)dst = hv;
    *(bf16x8*)(dst + 512) = lv;
}

// ======== shared MFMA phase (reads Ah/Al XOR-swizzled LDS + wp) ========
// Ah/Al layout: 16B block at LDS slot (row, s) holds row's k-block (s ^ (row&7))
#define MFMA_PHASE(Ah, Al, wp, isd, H)                                          \
    const int w = t >> 6, l = t & 63;                                           \
    const int m0 = (w >> 1) * 32;                                               \
    const int oh = w & 1;                                                       \
    const int lr = l & 15, lg = l >> 4;                                         \
    f32x4 acc[2][4];                                                            \
    _Pragma("unroll") for (int mf = 0; mf < 2; ++mf)                            \
        _Pragma("unroll") for (int fi = 0; fi < 4; ++fi)                        \
            acc[mf][fi] = (f32x4){0.f, 0.f, 0.f, 0.f};                          \
    _Pragma("unroll 2") for (int s = 0; s < 4; ++s) {                           \
        bf16x8 a_h[2], a_l[2], b_h[4], b_l[4];                                  \
        _Pragma("unroll") for (int fi = 0; fi < 4; ++fi) {                      \
            const int fg = oh * 4 + fi;                                         \
            const short* ph = wp + (size_t)((s * 8 + fg) * 2) * 512 + l * 8;    \
            b_h[fi] = *(const bf16x8*)ph;                                       \
            b_l[fi] = *(const bf16x8*)(ph + 512);                               \
        }                                                                       \
        _Pragma("unroll") for (int mf = 0; mf < 2; ++mf) {                      \
            const int row = m0 + mf * 16 + lr;                                  \
            const int kblk = (s * 4 + lg) ^ (l & 7);                            \
            a_h[mf] = *(const bf16x8*)(Ah + row * 128 + kblk * 8);              \
            a_l[mf] = *(const bf16x8*)(Al + row * 128 + kblk * 8);              \
        }                                                                       \
        _Pragma("unroll") for (int mf = 0; mf < 2; ++mf)                        \
            _Pragma("unroll") for (int fi = 0; fi < 4; ++fi) {                  \
                acc[mf][fi] = __builtin_amdgcn_mfma_f32_16x16x32_bf16(          \
                    a_l[mf], b_h[fi], acc[mf][fi], 0, 0, 0);                    \
                acc[mf][fi] = __builtin_amdgcn_mfma_f32_16x16x32_bf16(          \
                    a_h[mf], b_l[fi], acc[mf][fi], 0, 0, 0);                    \
                acc[mf][fi] = __builtin_amdgcn_mfma_f32_16x16x32_bf16(          \
                    a_h[mf], b_h[fi], acc[mf][fi], 0, 0, 0);                    \
            }                                                                   \
    }                                                                           \
    _Pragma("unroll") for (int mf = 0; mf < 2; ++mf)                            \
        _Pragma("unroll") for (int r = 0; r < 4; ++r) {                         \
            const int m = bm + m0 + mf * 16 + lg * 4 + r;                       \
            const float sd = isd[m];                                            \
            _Pragma("unroll") for (int fi = 0; fi < 4; ++fi)                    \
                H[(size_t)m * NC + oh * 64 + fi * 16 + lr] =                    \
                    acc[mf][fi][r] * sd;                                        \
        }

// ---------------- L0 matmul: fp32 input, in-kernel split (R6 path) ----------
__global__ __launch_bounds__(256) void matmul_f32(const float* __restrict__ X,
                                                  const short* __restrict__ wp,
                                                  const float* __restrict__ isd,
                                                  float* __restrict__ H) {
    __shared__ short Ah[64 * 128];
    __shared__ short Al[64 * 128];
    const int t = threadIdx.x;
    const int bm = blockIdx.x * BM;
#pragma unroll
    for (int j = 0; j < 8; ++j) {
        const int fi = j * 256 + t;
        const int row = fi >> 5;
        const int k0 = (t & 31) * 4;
        const float4 v = *(const float4*)(X + (size_t)bm * NC + (size_t)fi * 4);
        const float xs[4] = {v.x, v.y, v.z, v.w};
        short4v hi, lo;
#pragma unroll
        for (int e = 0; e < 4; ++e) {
            const short h = f2bf(xs[e]);
            hi[e] = h;
            lo[e] = f2bf(xs[e] - bf2f(h));
        }
        const int kblk = k0 >> 3;
        const int dst = row * 128 + ((kblk ^ (row & 7)) << 3) + (k0 & 7);
        *(short4v*)(Ah + dst) = hi;
        *(short4v*)(Al + dst) = lo;
    }
    __syncthreads();
    MFMA_PHASE(Ah, Al, wp, isd, H)
}

// ---------------- L1/L2 matmul: pre-split bf16 input via global_load_lds ----
__global__ __launch_bounds__(256) void matmul_split(const short* __restrict__ Xh,
                                                    const short* __restrict__ Xl,
                                                    const short* __restrict__ wp,
                                                    const float* __restrict__ isd,
                                                    float* __restrict__ H) {
    __shared__ short Ah[64 * 128];
    __shared__ short Al[64 * 128];
    const int t = threadIdx.x;
    const int bm = blockIdx.x * BM;
    {
        const int wv = t >> 6, ln = t & 63;
        const int cbase0 = wv * 256;  // this wave's 256 chunks (of 1024)
#pragma unroll
        for (int i = 0; i < 4; ++i) {
            const int cbase = cbase0 + i * 64;
            const int cidx = cbase + ln;
            const int r = cidx >> 4, sl = cidx & 15;
            const int kg = sl ^ (r & 7);  // global k-block to fetch for this slot
            const size_t goff = (size_t)(bm + r) * NC + kg * 8;
            __builtin_amdgcn_global_load_lds(
                (const __attribute__((address_space(1))) void*)(Xh + goff),
                (__attribute__((address_space(3))) void*)(Ah + (size_t)cbase * 8),
                16, 0, 0);
            __builtin_amdgcn_global_load_lds(
                (const __attribute__((address_space(1))) void*)(Xl + goff),
                (__attribute__((address_space(3))) void*)(Al + (size_t)cbase * 8),
                16, 0, 0);
        }
    }
    __syncthreads();
    MFMA_PHASE(Ah, Al, wp, isd, H)
}

// ---------------- gather: 2 nodes per wave, float4 lanes ----------------
// out = elu((gather_sum(H) + H_self) * isd); SPLIT: write bf16 hi/lo arrays
template <bool SPLIT>
__global__ __launch_bounds__(256) void gather2_kernel(
    const float* __restrict__ H, const int* __restrict__ ei,
    const float* __restrict__ isd, float* __restrict__ outf,
    short* __restrict__ Xh, short* __restrict__ Xl) {
    const int t = threadIdx.x;
    const int w = t >> 6, l = t & 63;
    const int g0 = blockIdx.x * 8 + w * 2;  // pair base (same batch item: NN even)
    const int gh = g0 + (l >> 5);           // this half-wave's node
    const int base = (g0 / NN) * NN;
    // lanes 0-15 hold node A's edges, lanes 32-47 node B's (16-31/48-63 dup)
    const int ev = ei[(size_t)gh * NE + (l & 15)];
    const float4* h4 = (const float4*)H;
    const int c4 = l & 31;  // float4-chunk within row
    float4 acc = h4[(size_t)gh * 32 + c4];  // self
#pragma unroll
    for (int q = 0; q < NE; ++q) {
        const int e = __shfl(ev, (l & 32) + q);  // uniform per half-wave
        const int row = base + (e & ~(e >> 31)); // base + max(e,0)
        const float4 v = h4[(size_t)row * 32 + c4];
        if (e >= 0) { acc.x += v.x; acc.y += v.y; acc.z += v.z; acc.w += v.w; }
    }
    const float sd = isd[gh];
    float o[4] = {acc.x * sd, acc.y * sd, acc.z * sd, acc.w * sd};
#pragma unroll
    for (int j = 0; j < 4; ++j) o[j] = o[j] > 0.f ? o[j] : (__expf(o[j]) - 1.f);
    if (SPLIT) {
        short4v hi, lo;
#pragma unroll
        for (int j = 0; j < 4; ++j) {
            const short hb = f2bf(o[j]);
            hi[j] = hb;
            lo[j] = f2bf(o[j] - bf2f(hb));
        }
        *(short4v*)(Xh + (size_t)gh * NC + c4 * 4) = hi;
        *(short4v*)(Xl + (size_t)gh * NC + c4 * 4) = lo;
    } else {
        float4 ov = {o[0], o[1], o[2], o[3]};
        *(float4*)(outf + (size_t)gh * NC + c4 * 4) = ov;
    }
}

extern "C" void kernel_launch(void* const* d_in, const int* in_sizes, int n_in,
                              void* d_out, int out_size, void* d_ws, size_t ws_size,
                              hipStream_t stream) {
    const float* x = (const float*)d_in[0];
    const int* ei = (const int*)d_in[1];
    const float* W0 = (const float*)d_in[2];
    const float* W1 = (const float*)d_in[3];
    const float* W2 = (const float*)d_in[4];
    float* out = (float*)d_out;

    float* isd = (float*)d_ws;                          // 320 KB
    short* wp0 = (short*)((char*)d_ws + (320 << 10));   // 64 KB
    short* wp1 = (short*)((char*)d_ws + (384 << 10));   // 64 KB
    short* wp2 = (short*)((char*)d_ws + (448 << 10));   // 64 KB
    float* h = (float*)((char*)d_ws + (512 << 10));     // 40.96 MB

    // inter-layer split-bf16 activations live inside d_out (exactly 41 MB)
    short* Xh = (short*)d_out;
    short* Xl = Xh + (size_t)M_TOTAL * NC;

    isd_kernel<<<(M_TOTAL + 255) / 256, 256, 0, stream>>>(ei, isd);
    wpack_kernel<<<8, 256, 0, stream>>>(W0, wp0);
    wpack_kernel<<<8, 256, 0, stream>>>(W1, wp1);
    wpack_kernel<<<8, 256, 0, stream>>>(W2, wp2);

    // L0: x (fp32) -> h -> split activations in d_out
    matmul_f32<<<M_TOTAL / BM, 256, 0, stream>>>(x, wp0, isd, h);
    gather2_kernel<true><<<M_TOTAL / 8, 256, 0, stream>>>(h, ei, isd, nullptr, Xh, Xl);
    // L1
    matmul_split<<<M_TOTAL / BM, 256, 0, stream>>>(Xh, Xl, wp1, isd, h);
    gather2_kernel<true><<<M_TOTAL / 8, 256, 0, stream>>>(h, ei, isd, nullptr, Xh, Xl);
    // L2: final gather writes fp32 d_out
    matmul_split<<<M_TOTAL / BM, 256, 0, stream>>>(Xh, Xl, wp2, isd, h);
    gather2_kernel<false><<<M_TOTAL / 8, 256, 0, stream>>>(h, ei, isd, out, nullptr, nullptr);
}